// Round 4
// baseline (1564.046 us; speedup 1.0000x reference)
//
#include <hip/hip_runtime.h>

#define NF0 300
#define F1 128
#define F2 64

// ---------------- CSR build ----------------

__global__ void hist_k(const int* __restrict__ dst, int* __restrict__ cnt, int E) {
    int i = blockIdx.x * blockDim.x + threadIdx.x;
    int stride = gridDim.x * blockDim.x;
    for (; i < E; i += stride) atomicAdd(&cnt[dst[i]], 1);
}

__global__ __launch_bounds__(1024) void scanA_k(const int* __restrict__ cnt, int* __restrict__ offs,
                                                int* __restrict__ partials, int n) {
    __shared__ int s[1024];
    int i = blockIdx.x * 1024 + threadIdx.x;
    int v = (i < n) ? cnt[i] : 0;
    s[threadIdx.x] = v;
    __syncthreads();
    for (int d = 1; d < 1024; d <<= 1) {
        int t = (threadIdx.x >= (unsigned)d) ? s[threadIdx.x - d] : 0;
        __syncthreads();
        s[threadIdx.x] += t;
        __syncthreads();
    }
    if (i < n) offs[i] = s[threadIdx.x] - v;  // exclusive within chunk
    if (threadIdx.x == 1023) partials[blockIdx.x] = s[1023];
}

__global__ __launch_bounds__(128) void scanB_k(int* __restrict__ partials, int nchunks) {
    __shared__ int s[128];
    int v = (threadIdx.x < nchunks) ? partials[threadIdx.x] : 0;
    s[threadIdx.x] = v;
    __syncthreads();
    for (int d = 1; d < 128; d <<= 1) {
        int t = (threadIdx.x >= (unsigned)d) ? s[threadIdx.x - d] : 0;
        __syncthreads();
        s[threadIdx.x] += t;
        __syncthreads();
    }
    if (threadIdx.x < nchunks) partials[threadIdx.x] = s[threadIdx.x] - v;  // exclusive
}

__global__ void scanC_k(int* __restrict__ offs, const int* __restrict__ partials, int* __restrict__ cursor,
                        const int* __restrict__ cnt, float* __restrict__ dinv, int n, int E) {
    int i = blockIdx.x * blockDim.x + threadIdx.x;
    if (i < n) {
        int o = offs[i] + partials[i >> 10];
        offs[i] = o;
        cursor[i] = o;
        dinv[i] = rsqrtf((float)cnt[i] + 1.0f);  // +1 self-loop; deg>=1 always
    }
    if (i == 0) offs[n] = E;
}

__global__ void fill_k(const int* __restrict__ src, const int* __restrict__ dst, int* __restrict__ cursor,
                       int* __restrict__ slots, int E) {
    int i = blockIdx.x * blockDim.x + threadIdx.x;
    int stride = gridDim.x * blockDim.x;
    for (; i < E; i += stride) {
        int d = dst[i];
        int p = atomicAdd(&cursor[d], 1);
        slots[p] = src[i];
    }
}

// ---------------- GEMM1: W-chunks in VGPR, x via VMEM broadcast, NO LDS / NO SMEM in hot loop ----
// Wave = 8 rows x 64 cols (half = wid&1). K in 5 chunks of 60 held in VGPRs (lane = col).
// Inner loop is vmcnt-only: 8 independent b128 broadcast loads + 32 FMAs per k4 step.
__global__ __launch_bounds__(256, 4) void gemm1_k(const float* __restrict__ x, const float* __restrict__ W1,
                                                  const float* __restrict__ dinv, float* __restrict__ y1, int n) {
    int zero;
    asm volatile("v_mov_b32 %0, 0" : "=v"(zero));  // opaque per-lane 0: defeats s_load scalarization
    int lane = threadIdx.x & 63;
    int w = (blockIdx.x * 256 + threadIdx.x) >> 6;
    int half = w & 1;
    int r0 = (w >> 1) << 3;
    if (r0 >= n) return;
    int cbase = (half << 6) + lane;
    const float* xb = x + zero;  // VGPR-based address -> global_load (vmcnt)
    float acc[8] = {0.f, 0.f, 0.f, 0.f, 0.f, 0.f, 0.f, 0.f};

    if (r0 + 8 <= n) {
        const float* xr = xb + (size_t)r0 * NF0;
        for (int kc = 0; kc < 5; ++kc) {   // K chunks of 60
            int k0 = kc * 60;
            float wreg[60];
#pragma unroll
            for (int j = 0; j < 60; ++j) wreg[j] = W1[(k0 + j) * F1 + cbase];  // coalesced 256B
#pragma unroll
            for (int k4 = 0; k4 < 60; k4 += 4) {
                float4 xv[8];
#pragma unroll
                for (int r = 0; r < 8; ++r)
                    xv[r] = *(const float4*)(xr + r * NF0 + k0 + k4);  // 16B broadcast, vmcnt
#pragma unroll
                for (int r = 0; r < 8; ++r) {
                    acc[r] = fmaf(xv[r].x, wreg[k4], acc[r]);
                    acc[r] = fmaf(xv[r].y, wreg[k4 + 1], acc[r]);
                    acc[r] = fmaf(xv[r].z, wreg[k4 + 2], acc[r]);
                    acc[r] = fmaf(xv[r].w, wreg[k4 + 3], acc[r]);
                }
            }
        }
#pragma unroll
        for (int r = 0; r < 8; ++r)
            y1[(size_t)(r0 + r) * F1 + cbase] = acc[r] * dinv[r0 + r];
    } else {  // safety tail (n%8==0 for this problem; never taken)
        for (int r = r0; r < n; ++r) {
            float a = 0.f;
            for (int k = 0; k < NF0; ++k) a = fmaf(xb[(size_t)r * NF0 + k], W1[k * F1 + cbase], a);
            y1[(size_t)r * F1 + cbase] = a * dinv[r];
        }
    }
}

// ---------------- GEMM2: same structure; 64 cols, K=128 in 2 chunks of 64 ----------------
__global__ __launch_bounds__(256, 4) void gemm2_k(const float* __restrict__ h, const float* __restrict__ W2,
                                                  const float* __restrict__ dinv, float* __restrict__ y2, int n) {
    int zero;
    asm volatile("v_mov_b32 %0, 0" : "=v"(zero));
    int lane = threadIdx.x & 63;
    int w = (blockIdx.x * 256 + threadIdx.x) >> 6;
    int r0 = w << 3;
    if (r0 >= n) return;
    const float* hb = h + zero;
    float acc[8] = {0.f, 0.f, 0.f, 0.f, 0.f, 0.f, 0.f, 0.f};

    if (r0 + 8 <= n) {
        const float* hr = hb + (size_t)r0 * F1;
        for (int kc = 0; kc < 2; ++kc) {
            int k0 = kc * 64;
            float wreg[64];
#pragma unroll
            for (int j = 0; j < 64; ++j) wreg[j] = W2[(k0 + j) * F2 + lane];
#pragma unroll
            for (int k4 = 0; k4 < 64; k4 += 4) {
                float4 hv[8];
#pragma unroll
                for (int r = 0; r < 8; ++r)
                    hv[r] = *(const float4*)(hr + r * F1 + k0 + k4);
#pragma unroll
                for (int r = 0; r < 8; ++r) {
                    acc[r] = fmaf(hv[r].x, wreg[k4], acc[r]);
                    acc[r] = fmaf(hv[r].y, wreg[k4 + 1], acc[r]);
                    acc[r] = fmaf(hv[r].z, wreg[k4 + 2], acc[r]);
                    acc[r] = fmaf(hv[r].w, wreg[k4 + 3], acc[r]);
                }
            }
        }
#pragma unroll
        for (int r = 0; r < 8; ++r)
            y2[(size_t)(r0 + r) * F2 + lane] = acc[r] * dinv[r0 + r];
    } else {
        for (int r = r0; r < n; ++r) {
            float a = 0.f;
            for (int k = 0; k < F1; ++k) a = fmaf(hb[(size_t)r * F1 + k], W2[k * F2 + lane], a);
            y2[(size_t)r * F2 + lane] = a * dinv[r];
        }
    }
}

// ---------------- Pull aggregation (CSR; wave-per-node; 8 gathers in flight) ----------------

__global__ __launch_bounds__(256) void agg1_k(const float* __restrict__ y1, const int* __restrict__ offs,
                                              const int* __restrict__ slots, const float* __restrict__ dinv,
                                              const float* __restrict__ b1, float* __restrict__ hrelu, int n) {
    int gtid = blockIdx.x * 256 + threadIdx.x;
    int wid = gtid >> 6, lane = threadIdx.x & 63;
    int nw = (gridDim.x * 256) >> 6;
    int c = lane * 2;
    for (int i = wid; i < n; i += nw) {
        int row = __builtin_amdgcn_readfirstlane(i);
        int beg = offs[row], end = offs[row + 1];
        float2 acc = *(const float2*)(y1 + (size_t)row * F1 + c);  // self-loop term
        int j = beg;
        while (j < end) {
            int m = min(64, end - j);
            int sv = (lane < m) ? slots[j + lane] : 0;
            int t = 0;
            for (; t + 8 <= m; t += 8) {  // 8 gathers in flight
                float2 v0 = *(const float2*)(y1 + (size_t)__shfl(sv, t) * F1 + c);
                float2 v1 = *(const float2*)(y1 + (size_t)__shfl(sv, t + 1) * F1 + c);
                float2 v2 = *(const float2*)(y1 + (size_t)__shfl(sv, t + 2) * F1 + c);
                float2 v3 = *(const float2*)(y1 + (size_t)__shfl(sv, t + 3) * F1 + c);
                float2 v4 = *(const float2*)(y1 + (size_t)__shfl(sv, t + 4) * F1 + c);
                float2 v5 = *(const float2*)(y1 + (size_t)__shfl(sv, t + 5) * F1 + c);
                float2 v6 = *(const float2*)(y1 + (size_t)__shfl(sv, t + 6) * F1 + c);
                float2 v7 = *(const float2*)(y1 + (size_t)__shfl(sv, t + 7) * F1 + c);
                acc.x += ((v0.x + v1.x) + (v2.x + v3.x)) + ((v4.x + v5.x) + (v6.x + v7.x));
                acc.y += ((v0.y + v1.y) + (v2.y + v3.y)) + ((v4.y + v5.y) + (v6.y + v7.y));
            }
            for (; t < m; ++t) {
                float2 v = *(const float2*)(y1 + (size_t)__shfl(sv, t) * F1 + c);
                acc.x += v.x;
                acc.y += v.y;
            }
            j += m;
        }
        float dv = dinv[row];
        float2 bb = *(const float2*)(b1 + c);
        float2 hv;
        hv.x = fmaxf(fmaf(acc.x, dv, bb.x), 0.f);
        hv.y = fmaxf(fmaf(acc.y, dv, bb.y), 0.f);
        *(float2*)(hrelu + (size_t)row * F1 + c) = hv;
    }
}

__global__ __launch_bounds__(256) void agg2_k(const float* __restrict__ y2, const int* __restrict__ offs,
                                              const int* __restrict__ slots, const float* __restrict__ dinv,
                                              const float* __restrict__ b2, float* __restrict__ out, int n) {
    int gtid = blockIdx.x * 256 + threadIdx.x;
    int wid = gtid >> 6, lane = threadIdx.x & 63;
    int nw = (gridDim.x * 256) >> 6;
    for (int i = wid; i < n; i += nw) {
        int row = __builtin_amdgcn_readfirstlane(i);
        int beg = offs[row], end = offs[row + 1];
        float acc = y2[(size_t)row * F2 + lane];  // self-loop term
        int j = beg;
        while (j < end) {
            int m = min(64, end - j);
            int sv = (lane < m) ? slots[j + lane] : 0;
            int t = 0;
            for (; t + 8 <= m; t += 8) {
                float v0 = y2[(size_t)__shfl(sv, t) * F2 + lane];
                float v1 = y2[(size_t)__shfl(sv, t + 1) * F2 + lane];
                float v2 = y2[(size_t)__shfl(sv, t + 2) * F2 + lane];
                float v3 = y2[(size_t)__shfl(sv, t + 3) * F2 + lane];
                float v4 = y2[(size_t)__shfl(sv, t + 4) * F2 + lane];
                float v5 = y2[(size_t)__shfl(sv, t + 5) * F2 + lane];
                float v6 = y2[(size_t)__shfl(sv, t + 6) * F2 + lane];
                float v7 = y2[(size_t)__shfl(sv, t + 7) * F2 + lane];
                acc += ((v0 + v1) + (v2 + v3)) + ((v4 + v5) + (v6 + v7));
            }
            for (; t < m; ++t) acc += y2[(size_t)__shfl(sv, t) * F2 + lane];
            j += m;
        }
        out[(size_t)row * F2 + lane] = fmaf(acc, dinv[row], b2[lane]);
    }
}

// ---------------- launch ----------------

extern "C" void kernel_launch(void* const* d_in, const int* in_sizes, int n_in,
                              void* d_out, int out_size, void* d_ws, size_t ws_size,
                              hipStream_t stream) {
    const float* x  = (const float*)d_in[0];
    const int*   ei = (const int*)d_in[1];
    const float* W1 = (const float*)d_in[2];
    const float* b1 = (const float*)d_in[3];
    const float* W2 = (const float*)d_in[4];
    const float* b2 = (const float*)d_in[5];
    float* out = (float*)d_out;

    int n = in_sizes[0] / NF0;
    int E = in_sizes[1] / 2;
    const int* srcv = ei;      // edge_index[0]
    const int* dstv = ei + E;  // edge_index[1]

    char* ws = (char*)d_ws;
    size_t off = 0;
    auto alloc = [&](size_t bytes) -> void* {
        void* p = ws + off;
        off = (off + bytes + 255) & ~(size_t)255;
        return p;
    };
    float* dinv   = (float*)alloc((size_t)n * 4);
    int* cnt      = (int*)alloc((size_t)n * 4);
    int* offs     = (int*)alloc((size_t)(n + 1) * 4);
    int* cursor   = (int*)alloc((size_t)n * 4);
    int* partials = (int*)alloc(((size_t)(n + 1023) / 1024) * 4);
    int* slots    = (int*)alloc((size_t)E * 4);
    float* y1     = (float*)alloc((size_t)n * F1 * 4);
    float* hrelu  = (float*)alloc((size_t)n * F1 * 4);
    float* y2     = y1;  // y1 dead after agg1; reuse

    int nchunks = (n + 1023) / 1024;

    hipMemsetAsync(cnt, 0, (size_t)n * 4, stream);
    hist_k<<<4096, 256, 0, stream>>>(dstv, cnt, E);
    scanA_k<<<nchunks, 1024, 0, stream>>>(cnt, offs, partials, n);
    scanB_k<<<1, 128, 0, stream>>>(partials, nchunks);
    scanC_k<<<(n + 255) / 256, 256, 0, stream>>>(offs, partials, cursor, cnt, dinv, n, E);
    fill_k<<<4096, 256, 0, stream>>>(srcv, dstv, cursor, slots, E);

    int waves1 = ((n + 7) / 8) * 2;               // 8 rows/wave x 2 col-halves
    int g1_blocks = (waves1 + 3) / 4;             // 4 waves/block
    int waves2 = (n + 7) / 8;
    int g2_blocks = (waves2 + 3) / 4;
    gemm1_k<<<g1_blocks, 256, 0, stream>>>(x, W1, dinv, y1, n);
    agg1_k<<<2048, 256, 0, stream>>>(y1, offs, slots, dinv, b1, hrelu, n);
    gemm2_k<<<g2_blocks, 256, 0, stream>>>(hrelu, W2, dinv, y2, n);
    agg2_k<<<2048, 256, 0, stream>>>(y2, offs, slots, dinv, b2, out, n);
}

// Round 5
// 1026.757 us; speedup vs baseline: 1.5233x; 1.5233x over previous
//
#include <hip/hip_runtime.h>

#define NF0 300
#define F1 128
#define F2 64

// ---------------- CSR build ----------------

__global__ void hist_k(const int* __restrict__ dst, int* __restrict__ cnt, int E) {
    int i = blockIdx.x * blockDim.x + threadIdx.x;
    int stride = gridDim.x * blockDim.x;
    for (; i < E; i += stride) atomicAdd(&cnt[dst[i]], 1);
}

__global__ __launch_bounds__(1024) void scanA_k(const int* __restrict__ cnt, int* __restrict__ offs,
                                                int* __restrict__ partials, int n) {
    __shared__ int s[1024];
    int i = blockIdx.x * 1024 + threadIdx.x;
    int v = (i < n) ? cnt[i] : 0;
    s[threadIdx.x] = v;
    __syncthreads();
    for (int d = 1; d < 1024; d <<= 1) {
        int t = (threadIdx.x >= (unsigned)d) ? s[threadIdx.x - d] : 0;
        __syncthreads();
        s[threadIdx.x] += t;
        __syncthreads();
    }
    if (i < n) offs[i] = s[threadIdx.x] - v;  // exclusive within chunk
    if (threadIdx.x == 1023) partials[blockIdx.x] = s[1023];
}

__global__ __launch_bounds__(128) void scanB_k(int* __restrict__ partials, int nchunks) {
    __shared__ int s[128];
    int v = (threadIdx.x < nchunks) ? partials[threadIdx.x] : 0;
    s[threadIdx.x] = v;
    __syncthreads();
    for (int d = 1; d < 128; d <<= 1) {
        int t = (threadIdx.x >= (unsigned)d) ? s[threadIdx.x - d] : 0;
        __syncthreads();
        s[threadIdx.x] += t;
        __syncthreads();
    }
    if (threadIdx.x < nchunks) partials[threadIdx.x] = s[threadIdx.x] - v;  // exclusive
}

__global__ void scanC_k(int* __restrict__ offs, const int* __restrict__ partials, int* __restrict__ cursor,
                        const int* __restrict__ cnt, float* __restrict__ dinv, int n, int E) {
    int i = blockIdx.x * blockDim.x + threadIdx.x;
    if (i < n) {
        int o = offs[i] + partials[i >> 10];
        offs[i] = o;
        cursor[i] = o;
        dinv[i] = rsqrtf((float)cnt[i] + 1.0f);  // +1 self-loop; deg>=1 always
    }
    if (i == 0) offs[n] = E;
}

__global__ void fill_k(const int* __restrict__ src, const int* __restrict__ dst, int* __restrict__ cursor,
                       int* __restrict__ slots, int E) {
    int i = blockIdx.x * blockDim.x + threadIdx.x;
    int stride = gridDim.x * blockDim.x;
    for (; i < E; i += stride) {
        int d = dst[i];
        int p = atomicAdd(&cursor[d], 1);
        slots[p] = src[i];
    }
}

// ---------------- GEMM1: canonical LDS-tiled, 128x128 tile, 8x8 micro-tile ----------------
// 256 thr: cx=tid&15 (cols cx*8..+7), ry=tid>>4 (rows ry*8..+7). K_TILE=20 (300=15*20).
// Per k: 4 ds_read_b128 + 64 FMA -> VALU-bound. As transposed [k][row], pad 132 (A reads 2-way free).
__global__ __launch_bounds__(256) void gemm1_k(const float* __restrict__ x, const float* __restrict__ W1,
                                               const float* __restrict__ dinv, float* __restrict__ y1, int n) {
    __shared__ float As[20][132];  // 10.56 KB
    __shared__ float Bs[20][128];  // 10.24 KB
    int tid = threadIdx.x;
    int cx = tid & 15;
    int ry = tid >> 4;
    int rowbase = blockIdx.x * 128;
    float acc[8][8];
#pragma unroll
    for (int i = 0; i < 8; ++i)
#pragma unroll
        for (int j = 0; j < 8; ++j) acc[i][j] = 0.f;

    int srow = tid >> 1;   // 2 threads per row, 10 floats each
    int shalf = tid & 1;
    int grow = min(rowbase + srow, n - 1);
    const float* xrow = x + (size_t)grow * NF0 + shalf * 10;

    for (int kt = 0; kt < NF0; kt += 20) {
        __syncthreads();
#pragma unroll
        for (int j = 0; j < 10; ++j) As[shalf * 10 + j][srow] = xrow[kt + j];
#pragma unroll
        for (int v = 0; v < 10; ++v) {
            int i = tid + v * 256;  // 0..2559
            int kk = i >> 7, col = i & 127;
            Bs[kk][col] = W1[(kt + kk) * F1 + col];
        }
        __syncthreads();
#pragma unroll
        for (int kk = 0; kk < 20; ++kk) {
            float a[8], b[8];
            *(float4*)&a[0] = *(const float4*)&As[kk][ry * 8];
            *(float4*)&a[4] = *(const float4*)&As[kk][ry * 8 + 4];
            *(float4*)&b[0] = *(const float4*)&Bs[kk][cx * 8];
            *(float4*)&b[4] = *(const float4*)&Bs[kk][cx * 8 + 4];
#pragma unroll
            for (int i = 0; i < 8; ++i)
#pragma unroll
                for (int j = 0; j < 8; ++j) acc[i][j] = fmaf(a[i], b[j], acc[i][j]);
        }
    }
#pragma unroll
    for (int i = 0; i < 8; ++i) {
        int row = rowbase + ry * 8 + i;
        if (row < n) {
            float dv = dinv[row];
            float o[8];
#pragma unroll
            for (int j = 0; j < 8; ++j) o[j] = acc[i][j] * dv;
            float* yp = y1 + (size_t)row * F1 + cx * 8;
            *(float4*)yp = *(float4*)&o[0];
            *(float4*)(yp + 4) = *(float4*)&o[4];
        }
    }
}

// ---------------- GEMM2: 256x64 tile, K_TILE=16, 8x8 micro-tile ----------------
// 256 thr: cx=tid&7 (cols cx*8), ry=tid>>3 (rows ry*8). Thread stages its own row (4 dwordx4).
__global__ __launch_bounds__(256) void gemm2_k(const float* __restrict__ h, const float* __restrict__ W2,
                                               const float* __restrict__ dinv, float* __restrict__ y2, int n) {
    __shared__ float As[16][260];  // 16.64 KB
    __shared__ float Bs[16][64];   // 4 KB
    int tid = threadIdx.x;
    int cx = tid & 7;
    int ry = tid >> 3;
    int rowbase = blockIdx.x * 256;
    float acc[8][8];
#pragma unroll
    for (int i = 0; i < 8; ++i)
#pragma unroll
        for (int j = 0; j < 8; ++j) acc[i][j] = 0.f;

    int grow = min(rowbase + tid, n - 1);
    const float* hrow = h + (size_t)grow * F1;

    for (int kt = 0; kt < F1; kt += 16) {
        __syncthreads();
        float4 t0 = *(const float4*)(hrow + kt);
        float4 t1 = *(const float4*)(hrow + kt + 4);
        float4 t2 = *(const float4*)(hrow + kt + 8);
        float4 t3 = *(const float4*)(hrow + kt + 12);
        As[0][tid] = t0.x;  As[1][tid] = t0.y;  As[2][tid] = t0.z;  As[3][tid] = t0.w;
        As[4][tid] = t1.x;  As[5][tid] = t1.y;  As[6][tid] = t1.z;  As[7][tid] = t1.w;
        As[8][tid] = t2.x;  As[9][tid] = t2.y;  As[10][tid] = t2.z; As[11][tid] = t2.w;
        As[12][tid] = t3.x; As[13][tid] = t3.y; As[14][tid] = t3.z; As[15][tid] = t3.w;
#pragma unroll
        for (int v = 0; v < 4; ++v) {
            int i = tid + v * 256;  // 0..1023
            int kk = i >> 6, col = i & 63;
            Bs[kk][col] = W2[(kt + kk) * F2 + col];
        }
        __syncthreads();
#pragma unroll
        for (int kk = 0; kk < 16; ++kk) {
            float a[8], b[8];
            *(float4*)&a[0] = *(const float4*)&As[kk][ry * 8];
            *(float4*)&a[4] = *(const float4*)&As[kk][ry * 8 + 4];
            *(float4*)&b[0] = *(const float4*)&Bs[kk][cx * 8];
            *(float4*)&b[4] = *(const float4*)&Bs[kk][cx * 8 + 4];
#pragma unroll
            for (int i = 0; i < 8; ++i)
#pragma unroll
                for (int j = 0; j < 8; ++j) acc[i][j] = fmaf(a[i], b[j], acc[i][j]);
        }
    }
#pragma unroll
    for (int i = 0; i < 8; ++i) {
        int row = rowbase + ry * 8 + i;
        if (row < n) {
            float dv = dinv[row];
            float o[8];
#pragma unroll
            for (int j = 0; j < 8; ++j) o[j] = acc[i][j] * dv;
            float* yp = y2 + (size_t)row * F2 + cx * 8;
            *(float4*)yp = *(float4*)&o[0];
            *(float4*)(yp + 4) = *(float4*)&o[4];
        }
    }
}

// ---------------- Pull aggregation (CSR; wave-per-node; 8 gathers in flight) ----------------

__global__ __launch_bounds__(256) void agg1_k(const float* __restrict__ y1, const int* __restrict__ offs,
                                              const int* __restrict__ slots, const float* __restrict__ dinv,
                                              const float* __restrict__ b1, float* __restrict__ hrelu, int n) {
    int gtid = blockIdx.x * 256 + threadIdx.x;
    int wid = gtid >> 6, lane = threadIdx.x & 63;
    int nw = (gridDim.x * 256) >> 6;
    int c = lane * 2;
    for (int i = wid; i < n; i += nw) {
        int row = __builtin_amdgcn_readfirstlane(i);
        int beg = offs[row], end = offs[row + 1];
        float2 acc = *(const float2*)(y1 + (size_t)row * F1 + c);  // self-loop term
        int j = beg;
        while (j < end) {
            int m = min(64, end - j);
            int sv = (lane < m) ? slots[j + lane] : 0;
            int t = 0;
            for (; t + 8 <= m; t += 8) {  // 8 gathers in flight
                float2 v0 = *(const float2*)(y1 + (size_t)__shfl(sv, t) * F1 + c);
                float2 v1 = *(const float2*)(y1 + (size_t)__shfl(sv, t + 1) * F1 + c);
                float2 v2 = *(const float2*)(y1 + (size_t)__shfl(sv, t + 2) * F1 + c);
                float2 v3 = *(const float2*)(y1 + (size_t)__shfl(sv, t + 3) * F1 + c);
                float2 v4 = *(const float2*)(y1 + (size_t)__shfl(sv, t + 4) * F1 + c);
                float2 v5 = *(const float2*)(y1 + (size_t)__shfl(sv, t + 5) * F1 + c);
                float2 v6 = *(const float2*)(y1 + (size_t)__shfl(sv, t + 6) * F1 + c);
                float2 v7 = *(const float2*)(y1 + (size_t)__shfl(sv, t + 7) * F1 + c);
                acc.x += ((v0.x + v1.x) + (v2.x + v3.x)) + ((v4.x + v5.x) + (v6.x + v7.x));
                acc.y += ((v0.y + v1.y) + (v2.y + v3.y)) + ((v4.y + v5.y) + (v6.y + v7.y));
            }
            for (; t < m; ++t) {
                float2 v = *(const float2*)(y1 + (size_t)__shfl(sv, t) * F1 + c);
                acc.x += v.x;
                acc.y += v.y;
            }
            j += m;
        }
        float dv = dinv[row];
        float2 bb = *(const float2*)(b1 + c);
        float2 hv;
        hv.x = fmaxf(fmaf(acc.x, dv, bb.x), 0.f);
        hv.y = fmaxf(fmaf(acc.y, dv, bb.y), 0.f);
        *(float2*)(hrelu + (size_t)row * F1 + c) = hv;
    }
}

__global__ __launch_bounds__(256) void agg2_k(const float* __restrict__ y2, const int* __restrict__ offs,
                                              const int* __restrict__ slots, const float* __restrict__ dinv,
                                              const float* __restrict__ b2, float* __restrict__ out, int n) {
    int gtid = blockIdx.x * 256 + threadIdx.x;
    int wid = gtid >> 6, lane = threadIdx.x & 63;
    int nw = (gridDim.x * 256) >> 6;
    for (int i = wid; i < n; i += nw) {
        int row = __builtin_amdgcn_readfirstlane(i);
        int beg = offs[row], end = offs[row + 1];
        float acc = y2[(size_t)row * F2 + lane];  // self-loop term
        int j = beg;
        while (j < end) {
            int m = min(64, end - j);
            int sv = (lane < m) ? slots[j + lane] : 0;
            int t = 0;
            for (; t + 8 <= m; t += 8) {
                float v0 = y2[(size_t)__shfl(sv, t) * F2 + lane];
                float v1 = y2[(size_t)__shfl(sv, t + 1) * F2 + lane];
                float v2 = y2[(size_t)__shfl(sv, t + 2) * F2 + lane];
                float v3 = y2[(size_t)__shfl(sv, t + 3) * F2 + lane];
                float v4 = y2[(size_t)__shfl(sv, t + 4) * F2 + lane];
                float v5 = y2[(size_t)__shfl(sv, t + 5) * F2 + lane];
                float v6 = y2[(size_t)__shfl(sv, t + 6) * F2 + lane];
                float v7 = y2[(size_t)__shfl(sv, t + 7) * F2 + lane];
                acc += ((v0 + v1) + (v2 + v3)) + ((v4 + v5) + (v6 + v7));
            }
            for (; t < m; ++t) acc += y2[(size_t)__shfl(sv, t) * F2 + lane];
            j += m;
        }
        out[(size_t)row * F2 + lane] = fmaf(acc, dinv[row], b2[lane]);
    }
}

// ---------------- launch ----------------

extern "C" void kernel_launch(void* const* d_in, const int* in_sizes, int n_in,
                              void* d_out, int out_size, void* d_ws, size_t ws_size,
                              hipStream_t stream) {
    const float* x  = (const float*)d_in[0];
    const int*   ei = (const int*)d_in[1];
    const float* W1 = (const float*)d_in[2];
    const float* b1 = (const float*)d_in[3];
    const float* W2 = (const float*)d_in[4];
    const float* b2 = (const float*)d_in[5];
    float* out = (float*)d_out;

    int n = in_sizes[0] / NF0;
    int E = in_sizes[1] / 2;
    const int* srcv = ei;      // edge_index[0]
    const int* dstv = ei + E;  // edge_index[1]

    char* ws = (char*)d_ws;
    size_t off = 0;
    auto alloc = [&](size_t bytes) -> void* {
        void* p = ws + off;
        off = (off + bytes + 255) & ~(size_t)255;
        return p;
    };
    float* dinv   = (float*)alloc((size_t)n * 4);
    int* cnt      = (int*)alloc((size_t)n * 4);
    int* offs     = (int*)alloc((size_t)(n + 1) * 4);
    int* cursor   = (int*)alloc((size_t)n * 4);
    int* partials = (int*)alloc(((size_t)(n + 1023) / 1024) * 4);
    int* slots    = (int*)alloc((size_t)E * 4);
    float* y1     = (float*)alloc((size_t)n * F1 * 4);
    float* hrelu  = (float*)alloc((size_t)n * F1 * 4);
    float* y2     = y1;  // y1 dead after agg1; reuse

    int nchunks = (n + 1023) / 1024;

    hipMemsetAsync(cnt, 0, (size_t)n * 4, stream);
    hist_k<<<4096, 256, 0, stream>>>(dstv, cnt, E);
    scanA_k<<<nchunks, 1024, 0, stream>>>(cnt, offs, partials, n);
    scanB_k<<<1, 128, 0, stream>>>(partials, nchunks);
    scanC_k<<<(n + 255) / 256, 256, 0, stream>>>(offs, partials, cursor, cnt, dinv, n, E);
    fill_k<<<4096, 256, 0, stream>>>(srcv, dstv, cursor, slots, E);

    gemm1_k<<<(n + 127) / 128, 256, 0, stream>>>(x, W1, dinv, y1, n);
    agg1_k<<<2048, 256, 0, stream>>>(y1, offs, slots, dinv, b1, hrelu, n);
    gemm2_k<<<(n + 255) / 256, 256, 0, stream>>>(hrelu, W2, dinv, y2, n);
    agg2_k<<<2048, 256, 0, stream>>>(y2, offs, slots, dinv, b2, out, n);
}